// Round 1
// baseline (149.801 us; speedup 1.0000x reference)
//
#include <hip/hip_runtime.h>
#include <hip/hip_bf16.h>
#include <stdint.h>

#define B_ 4096
#define L_ 80
#define V_ 256
#define H_ 512

typedef __attribute__((ext_vector_type(4))) float f32x4;
typedef __attribute__((ext_vector_type(8))) short bf16x8;

// ---------------------------------------------------------------------------
// Kernel 0: W2 [k=512][n=512] f32  ->  W2T [n=512][k=512] bf16
// thread i -> (n = i>>9, k = i&511); strided reads (L2-cached, 1 MB total),
// coalesced writes.
// ---------------------------------------------------------------------------
__global__ __launch_bounds__(256) void w2_transpose(
    const float* __restrict__ W2, __hip_bfloat16* __restrict__ W2T) {
  int i = blockIdx.x * blockDim.x + threadIdx.x;
  int n = i >> 9, k = i & 511;
  W2T[i] = __float2bfloat16(W2[k * H_ + n]);
}

// ---------------------------------------------------------------------------
// Kernel 1: gather-sum over 80 positions + b1 + relu -> h (bf16) [B][H]
// One block = 16 batch rows, 512 threads = one h-channel each.
// Loop l outer / b inner: the 16 gathered rows per step come from the same
// 512 KB W1 slice (position l) -> L2-resident reuse.
// ---------------------------------------------------------------------------
__global__ __launch_bounds__(512) void encode_gather(
    const int* __restrict__ msg, const float* __restrict__ W1,
    const float* __restrict__ b1, __hip_bfloat16* __restrict__ h) {
  const int BT = 16;
  __shared__ int offs[BT * L_];  // element offsets into W1
  const int t = threadIdx.x;
  const int b0 = blockIdx.x * BT;

  for (int i = t; i < BT * L_; i += 512) {
    int b = i / L_, l = i - b * L_;
    offs[i] = (l * V_ + msg[(b0 + b) * L_ + l]) * H_;
  }
  __syncthreads();

  float acc[BT];
#pragma unroll
  for (int b = 0; b < BT; ++b) acc[b] = 0.f;

  for (int l = 0; l < L_; ++l) {
#pragma unroll
    for (int b = 0; b < BT; ++b) {
      acc[b] += W1[offs[b * L_ + l] + t];  // 2KB coalesced row read
    }
  }

  const float bias = b1[t];
#pragma unroll
  for (int b = 0; b < BT; ++b) {
    float v = acc[b] + bias;
    v = v > 0.f ? v : 0.f;
    h[(size_t)(b0 + b) * H_ + t] = __float2bfloat16(v);
  }
}

// ---------------------------------------------------------------------------
// Kernel 2: out = relu(h @ W2 + b2), bf16 MFMA 16x16x32, fp32 accum/output.
// Block tile 64x64, 4 waves in 2x2, each wave 32x32 (2x2 fragments).
// A and B fragments use the SAME (lane,elem)->k mapping, so correctness is
// independent of the HW's internal k permutation. C/D: row=(lane>>4)*4+reg,
// col=lane&15 (m89-verified).
// ---------------------------------------------------------------------------
__global__ __launch_bounds__(256) void gemm_out(
    const __hip_bfloat16* __restrict__ h, const __hip_bfloat16* __restrict__ W2T,
    const float* __restrict__ b2, float* __restrict__ out) {
  const int wid = threadIdx.x >> 6;   // 0..3
  const int lane = threadIdx.x & 63;
  const int wm = wid >> 1, wn = wid & 1;
  const int bm = blockIdx.x * 64;
  const int bn = blockIdx.y * 64;
  const int lr = lane & 15;
  const int lq = lane >> 4;  // 0..3

  f32x4 acc[2][2] = {};

  const __hip_bfloat16* aptr0 = h + (size_t)(bm + wm * 32 + lr) * H_ + lq * 8;
  const __hip_bfloat16* bptr0 = W2T + (size_t)(bn + wn * 32 + lr) * H_ + lq * 8;

  for (int kt = 0; kt < H_ / 32; ++kt) {
    const int ko = kt * 32;
    bf16x8 a[2], bfr[2];
#pragma unroll
    for (int mi = 0; mi < 2; ++mi)
      a[mi] = *reinterpret_cast<const bf16x8*>(aptr0 + (size_t)mi * 16 * H_ + ko);
#pragma unroll
    for (int ni = 0; ni < 2; ++ni)
      bfr[ni] = *reinterpret_cast<const bf16x8*>(bptr0 + (size_t)ni * 16 * H_ + ko);
#pragma unroll
    for (int mi = 0; mi < 2; ++mi)
#pragma unroll
      for (int ni = 0; ni < 2; ++ni)
        acc[mi][ni] = __builtin_amdgcn_mfma_f32_16x16x32_bf16(
            a[mi], bfr[ni], acc[mi][ni], 0, 0, 0);
  }

#pragma unroll
  for (int mi = 0; mi < 2; ++mi) {
#pragma unroll
    for (int ni = 0; ni < 2; ++ni) {
      const int n = bn + wn * 32 + ni * 16 + lr;
      const float bias = b2[n];
#pragma unroll
      for (int r = 0; r < 4; ++r) {
        const int m = bm + wm * 32 + mi * 16 + lq * 4 + r;
        float v = acc[mi][ni][r] + bias;
        out[(size_t)m * H_ + n] = v > 0.f ? v : 0.f;
      }
    }
  }
}

// ---------------------------------------------------------------------------
extern "C" void kernel_launch(void* const* d_in, const int* in_sizes, int n_in,
                              void* d_out, int out_size, void* d_ws, size_t ws_size,
                              hipStream_t stream) {
  const int* msg   = (const int*)d_in[0];
  const float* W1  = (const float*)d_in[1];
  const float* b1  = (const float*)d_in[2];
  const float* W2  = (const float*)d_in[3];
  const float* b2  = (const float*)d_in[4];
  float* out = (float*)d_out;

  __hip_bfloat16* W2T = (__hip_bfloat16*)d_ws;                       // 512 KB
  __hip_bfloat16* h   = (__hip_bfloat16*)((char*)d_ws + H_ * H_ * 2); // 4 MB

  hipLaunchKernelGGL(w2_transpose, dim3((H_ * H_) / 256), dim3(256), 0, stream,
                     W2, W2T);
  hipLaunchKernelGGL(encode_gather, dim3(B_ / 16), dim3(512), 0, stream,
                     msg, W1, b1, h);
  hipLaunchKernelGGL(gemm_out, dim3(B_ / 64, H_ / 64), dim3(256), 0, stream,
                     h, W2T, b2, out);
}